// Round 1
// baseline (979.541 us; speedup 1.0000x reference)
//
#include <hip/hip_runtime.h>
#include <hip/hip_bf16.h>
#include <math.h>

#define DIM 1024
#define BATCH 16384
#define NLAYER 6

typedef __bf16 bf16_t;
typedef __attribute__((ext_vector_type(8))) __bf16 bf16x8;
typedef __attribute__((ext_vector_type(4))) float f32x4;

__device__ __forceinline__ void gload16(const void* g, void* l) {
  __builtin_amdgcn_global_load_lds(
      (const __attribute__((address_space(1))) void*)g,
      (__attribute__((address_space(3))) void*)l, 16, 0, 0);
}

// ---------------------------------------------------------------------------
// GEMM: C[m,n] = sum_k A[m,k] * W[n,k]   (A: [BATCH x DIM] bf16, W: [DIM x DIM] bf16)
// MODE 0: out = bf16( tanh(C + bias) )            -> outB
// MODE 1: h[m,n] = h*(1-ce-cc-cn) + C + bias + ce*e[n] + cc*c[n] + cn*nn[n]
// 128x128 tile, BK=32, 4 waves (2x2), each wave 4x4 of 16x16x32 MFMA (m97 structure)
// ---------------------------------------------------------------------------
template <int MODE>
__global__ __launch_bounds__(256) void gemm_kernel(
    const bf16_t* __restrict__ A, const bf16_t* __restrict__ W,
    const float* __restrict__ bias, bf16_t* __restrict__ outB,
    float* __restrict__ h, const f32x4* __restrict__ coef,
    const float* __restrict__ dirs) {
  __shared__ __align__(16) bf16_t sA[128 * 32];
  __shared__ __align__(16) bf16_t sB[128 * 32];
  const int tid = threadIdx.x;
  const int w = tid >> 6;
  const int lane = tid & 63;
  const int bm = blockIdx.x * 128;
  const int bn = blockIdx.y * 128;
  const int wm = (w & 1) * 64;
  const int wn = (w >> 1) * 64;
  const int lm = lane & 15;
  const int lkb = (lane >> 4) * 8;

  f32x4 acc[4][4] = {};

  // staging addresses: thread loads 8 bf16 (16B); 4 threads per row, 64 rows/pass
  const bf16_t* gA = A + (size_t)(bm + (tid >> 2)) * DIM + ((tid & 3) << 3);
  const bf16_t* gW = W + (size_t)(bn + (tid >> 2)) * DIM + ((tid & 3) << 3);
  char* lA = (char*)sA + w * 1024;  // wave-uniform LDS base (lane*16 implied)
  char* lB = (char*)sB + w * 1024;

  for (int kt = 0; kt < DIM; kt += 32) {
    gload16(gA + kt, lA);
    gload16(gA + kt + 64 * DIM, lA + 4096);
    gload16(gW + kt, lB);
    gload16(gW + kt + 64 * DIM, lB + 4096);
    __syncthreads();  // drains vmcnt -> LDS tiles complete
    bf16x8 aF[4], bF[4];
#pragma unroll
    for (int i = 0; i < 4; ++i)
      aF[i] = *(const bf16x8*)&sA[(wm + i * 16 + lm) * 32 + lkb];
#pragma unroll
    for (int j = 0; j < 4; ++j)
      bF[j] = *(const bf16x8*)&sB[(wn + j * 16 + lm) * 32 + lkb];
#pragma unroll
    for (int i = 0; i < 4; ++i)
#pragma unroll
      for (int j = 0; j < 4; ++j)
        acc[i][j] = __builtin_amdgcn_mfma_f32_16x16x32_bf16(aF[i], bF[j],
                                                            acc[i][j], 0, 0, 0);
    __syncthreads();  // compute done before next stage overwrites LDS
  }

  // C/D layout: col = lane&15, row = (lane>>4)*4 + reg   [m89/m91 verified]
  const int r0 = (lane >> 4) << 2;
#pragma unroll
  for (int i = 0; i < 4; ++i) {
    const int rowBase = bm + wm + i * 16 + r0;
    if constexpr (MODE == 1) {
      f32x4 cf[4];
#pragma unroll
      for (int r = 0; r < 4; ++r) cf[r] = coef[rowBase + r];
#pragma unroll
      for (int j = 0; j < 4; ++j) {
        const int col = bn + wn + j * 16 + lm;
        const float bv = bias[col];
        const float ev = dirs[col];
        const float cv = dirs[DIM + col];
        const float nv = dirs[2 * DIM + col];
#pragma unroll
        for (int r = 0; r < 4; ++r) {
          const size_t idx = (size_t)(rowBase + r) * DIM + col;
          const float hv = h[idx];
          h[idx] = hv * (1.f - cf[r].x - cf[r].y - cf[r].z) + acc[i][j][r] +
                   bv + cf[r].x * ev + cf[r].y * cv + cf[r].z * nv;
        }
      }
    } else {
#pragma unroll
      for (int j = 0; j < 4; ++j) {
        const int col = bn + wn + j * 16 + lm;
        const float bv = bias[col];
#pragma unroll
        for (int r = 0; r < 4; ++r)
          outB[(size_t)(rowBase + r) * DIM + col] =
              (bf16_t)tanhf(acc[i][j][r] + bv);
      }
    }
  }
}

// ---------------------------------------------------------------------------
// Per-row: reduce ||h||^2 and dots with e/c/n dirs; optional norm clamp at 10;
// write fp32 h, bf16 h, and the 3 force coefficients for the next layer.
//   coef.x = S_E*(1-a_e)/||h-e||, .y = S_C*(1-a_c)/||h-c||,
//   coef.z = (S_N*(1-a_n)+S_NB*boundary)/||h-n||
// using ||h-d||^2 = ||h||^2 - 2||h||a + 1 (d unit).
// ---------------------------------------------------------------------------
__global__ __launch_bounds__(256) void stats_kernel(
    const float* __restrict__ src, float* __restrict__ dst,
    bf16_t* __restrict__ dstb, f32x4* __restrict__ coef,
    const float* __restrict__ dirs, int doClamp, int writeAux) {
  const int row = blockIdx.x;
  const int t = threadIdx.x;
  const float4 v = ((const float4*)(src + (size_t)row * DIM))[t];
  const float4 e = ((const float4*)dirs)[t];
  const float4 c = ((const float4*)dirs)[t + 256];
  const float4 n = ((const float4*)dirs)[t + 512];
  float ss = v.x * v.x + v.y * v.y + v.z * v.z + v.w * v.w;
  float de = v.x * e.x + v.y * e.y + v.z * e.z + v.w * e.w;
  float dc = v.x * c.x + v.y * c.y + v.z * c.z + v.w * c.w;
  float dn = v.x * n.x + v.y * n.y + v.z * n.z + v.w * n.w;
#pragma unroll
  for (int off = 32; off; off >>= 1) {
    ss += __shfl_down(ss, off);
    de += __shfl_down(de, off);
    dc += __shfl_down(dc, off);
    dn += __shfl_down(dn, off);
  }
  __shared__ float red[4][4];
  __shared__ float fin[4];
  const int w = t >> 6;
  if ((t & 63) == 0) {
    red[w][0] = ss; red[w][1] = de; red[w][2] = dc; red[w][3] = dn;
  }
  __syncthreads();
  if (t == 0) {
    float a = 0, b = 0, cc = 0, d = 0;
#pragma unroll
    for (int i = 0; i < 4; ++i) {
      a += red[i][0]; b += red[i][1]; cc += red[i][2]; d += red[i][3];
    }
    fin[0] = a; fin[1] = b; fin[2] = cc; fin[3] = d;
  }
  __syncthreads();
  const float S = fin[0];
  const float norm = sqrtf(S);
  float scale = 1.f;
  if (doClamp && norm > 10.f) scale = 10.f / (norm + 1e-8f);
  float4 vo;
  vo.x = v.x * scale; vo.y = v.y * scale; vo.z = v.z * scale; vo.w = v.w * scale;
  ((float4*)(dst + (size_t)row * DIM))[t] = vo;
  if (writeAux) {
    union { bf16_t b[4]; uint2 u; } pk;
    pk.b[0] = (bf16_t)vo.x; pk.b[1] = (bf16_t)vo.y;
    pk.b[2] = (bf16_t)vo.z; pk.b[3] = (bf16_t)vo.w;
    ((uint2*)(dstb + (size_t)row * DIM))[t] = pk.u;
    if (t == 0) {
      const float invn = 1.f / fmaxf(norm, 1e-12f);
      const float ae = fin[1] * invn;  // scale-invariant
      const float ac = fin[2] * invn;
      const float an = fin[3] * invn;
      const float nc = norm * scale;   // clamped norm
      const float re = sqrtf(fmaxf(nc * nc - 2.f * nc * ae + 1.f, 0.f));
      const float rc = sqrtf(fmaxf(nc * nc - 2.f * nc * ac + 1.f, 0.f));
      const float rn = sqrtf(fmaxf(nc * nc - 2.f * nc * an + 1.f, 0.f));
      const float boundary = fminf(fmaxf(1.f - fabsf(ae - ac), 0.f), 1.f);
      f32x4 cf;
      cf.x = 0.1f * (1.f - ae) / fmaxf(re, 1e-12f);
      cf.y = 0.1f * (1.f - ac) / fmaxf(rc, 1e-12f);
      cf.z = (0.05f * (1.f - an) + 0.05f * boundary) / fmaxf(rn, 1e-12f);
      cf.w = 0.f;
      coef[row] = cf;
    }
  }
}

// Normalize the three anchors -> dirs[3*DIM]
__global__ __launch_bounds__(256) void prep_dirs(
    const float* __restrict__ ae, const float* __restrict__ ac,
    const float* __restrict__ an, float* __restrict__ dirs) {
  const int t = threadIdx.x;
  const float4 a = ((const float4*)ae)[t];
  const float4 b = ((const float4*)ac)[t];
  const float4 c = ((const float4*)an)[t];
  float sa = a.x * a.x + a.y * a.y + a.z * a.z + a.w * a.w;
  float sb = b.x * b.x + b.y * b.y + b.z * b.z + b.w * b.w;
  float sc = c.x * c.x + c.y * c.y + c.z * c.z + c.w * c.w;
#pragma unroll
  for (int off = 32; off; off >>= 1) {
    sa += __shfl_down(sa, off);
    sb += __shfl_down(sb, off);
    sc += __shfl_down(sc, off);
  }
  __shared__ float red[4][3];
  __shared__ float fin[3];
  const int w = t >> 6;
  if ((t & 63) == 0) { red[w][0] = sa; red[w][1] = sb; red[w][2] = sc; }
  __syncthreads();
  if (t == 0) {
    float x = 0, y = 0, z = 0;
#pragma unroll
    for (int i = 0; i < 4; ++i) { x += red[i][0]; y += red[i][1]; z += red[i][2]; }
    fin[0] = x; fin[1] = y; fin[2] = z;
  }
  __syncthreads();
  const float ia = 1.f / fmaxf(sqrtf(fin[0]), 1e-12f);
  const float ib = 1.f / fmaxf(sqrtf(fin[1]), 1e-12f);
  const float ic = 1.f / fmaxf(sqrtf(fin[2]), 1e-12f);
  float4 oa, ob, oc;
  oa.x = a.x * ia; oa.y = a.y * ia; oa.z = a.z * ia; oa.w = a.w * ia;
  ob.x = b.x * ib; ob.y = b.y * ib; ob.z = b.z * ib; ob.w = b.w * ib;
  oc.x = c.x * ic; oc.y = c.y * ic; oc.z = c.z * ic; oc.w = c.w * ic;
  ((float4*)dirs)[t] = oa;
  ((float4*)dirs)[t + 256] = ob;
  ((float4*)dirs)[t + 512] = oc;
}

__global__ __launch_bounds__(256) void cast_w_kernel(
    const float* __restrict__ W, bf16_t* __restrict__ Wb) {
  const int i = blockIdx.x * 256 + threadIdx.x;  // one float4 per thread
  const float4 v = ((const float4*)W)[i];
  union { bf16_t b[4]; uint2 u; } pk;
  pk.b[0] = (bf16_t)v.x; pk.b[1] = (bf16_t)v.y;
  pk.b[2] = (bf16_t)v.z; pk.b[3] = (bf16_t)v.w;
  ((uint2*)Wb)[i] = pk.u;
}

extern "C" void kernel_launch(void* const* d_in, const int* in_sizes, int n_in,
                              void* d_out, int out_size, void* d_ws,
                              size_t ws_size, hipStream_t stream) {
  const float* h0 = (const float*)d_in[0];
  const float* W1 = (const float*)d_in[1];
  const float* b1 = (const float*)d_in[2];
  const float* W2 = (const float*)d_in[3];
  const float* b2 = (const float*)d_in[4];
  const float* ae = (const float*)d_in[5];
  const float* ac = (const float*)d_in[6];
  const float* an = (const float*)d_in[7];
  float* h = (float*)d_out;

  char* ws = (char*)d_ws;
  bf16_t* hb = (bf16_t*)ws;  ws += (size_t)BATCH * DIM * 2;   // 32 MB
  bf16_t* Tb = (bf16_t*)ws;  ws += (size_t)BATCH * DIM * 2;   // 32 MB
  bf16_t* W1b = (bf16_t*)ws; ws += (size_t)DIM * DIM * 2;     // 2 MB
  bf16_t* W2b = (bf16_t*)ws; ws += (size_t)DIM * DIM * 2;     // 2 MB
  float* dirs = (float*)ws;  ws += 3 * DIM * 4;
  f32x4* coef = (f32x4*)ws;  ws += (size_t)BATCH * 16;

  prep_dirs<<<1, 256, 0, stream>>>(ae, ac, an, dirs);
  cast_w_kernel<<<DIM * DIM / 1024, 256, 0, stream>>>(W1, W1b);
  cast_w_kernel<<<DIM * DIM / 1024, 256, 0, stream>>>(W2, W2b);
  // init: copy h0 -> h (d_out), write bf16 copy + layer-0 coefficients
  stats_kernel<<<BATCH, 256, 0, stream>>>(h0, h, hb, coef, dirs, 0, 1);

  dim3 grid(BATCH / 128, DIM / 128);
  for (int l = 0; l < NLAYER; ++l) {
    gemm_kernel<0><<<grid, 256, 0, stream>>>(hb, W1b, b1, Tb, nullptr, nullptr,
                                             nullptr);
    gemm_kernel<1><<<grid, 256, 0, stream>>>(Tb, W2b, b2, nullptr, h, coef,
                                             dirs);
    stats_kernel<<<BATCH, 256, 0, stream>>>(h, h, hb, coef, dirs, 1,
                                            (l < NLAYER - 1) ? 1 : 0);
  }
}